// Round 9
// baseline (159.225 us; speedup 1.0000x reference)
//
#include <hip/hip_runtime.h>
#include <hip/hip_bf16.h>

// out[M=131072, N=512] = x[M, K=512] @ W^T[N=512, K=512] + bias[N]
// fp32 in/out; bf16 MFMA (fp32 accum).
//
// Kernel 1: repack W fp32 -> bf16 MFMA fragment blocks, kb-major:
//   wf block b = okb*32 + t (okb = 32-wide K unit 0..15, t = 16-col tile 0..31)
//   wf[(b*64 + l)*8 + j] = bf16(W[t*16 + (l&15)][okb*32 + (l>>4)*8 + j])
// Kernel 2: GEMM. Round-9 structural change: B is staged BLOCK-WIDE into LDS
//   via global_load_lds DMA (bf16 frag layout -> zero conversion, zero VGPR),
//   TRIPLE-buffered and issued 2 steps ahead with counted vmcnt(4) barriers
//   (never drained). Rounds 2-8 all had per-wave scattered B loads that miss
//   the stream-thrashed L2 and serialize ~800cy IC latency per step (the
//   structure-invariant ~150us). BM=128 also halves total B traffic to 512MB.
//   Geometry: 1024 thr = 16 waves (2 wrow x 8 wcol), wave tile 64x32 (acc=32),
//   BK=64, 16 steps = 2 N-passes x 8. A reg-staged 2 ahead, XOR-swizzled LDS
//   (reads AND writes at bank floor by construction).
//   LDS: B 3x32KB + A 2x16KB = 128KB -> 1 block/CU, 4 waves/SIMD.

#define M_TOTAL 131072
#define KDIM 512
#define NDIM 512
#define BM 128
#define NSTEP 16

typedef __attribute__((ext_vector_type(8))) short bf16x8;
typedef __attribute__((ext_vector_type(4))) float f32x4;
typedef __attribute__((ext_vector_type(4))) float fv4;
typedef __attribute__((ext_vector_type(4))) int iv4;
typedef __attribute__((ext_vector_type(2))) int iv2;

__device__ __forceinline__ unsigned short f2bf(float f) {
    union { float f; unsigned u; } c; c.f = f;
    unsigned r = c.u + 0x7fffu + ((c.u >> 16) & 1u);  // RNE
    return (unsigned short)(r >> 16);
}

__device__ __forceinline__ iv4 pack8(fv4 lo, fv4 hi) {
    union { unsigned short us[8]; iv4 v; } p;
#pragma unroll
    for (int i = 0; i < 4; ++i) { p.us[i] = f2bf(lo[i]); p.us[4 + i] = f2bf(hi[i]); }
    return p.v;
}

__device__ __forceinline__ void glds16(const void* g, void* l) {
    __builtin_amdgcn_global_load_lds(
        (const __attribute__((address_space(1))) void*)g,
        (__attribute__((address_space(3))) void*)l, 16, 0, 0);
}

__global__ void repack_w_kernel(const float* __restrict__ w,
                                unsigned short* __restrict__ wf) {
    const int gtid = blockIdx.x * 256 + threadIdx.x;  // 0..32767
    const int b = gtid >> 6, l = gtid & 63;
    const int okb = b >> 5, t = b & 31;
    const int n = t * 16 + (l & 15);
    const int k0 = okb * 32 + (l >> 4) * 8;
    const fv4* src = reinterpret_cast<const fv4*>(w + n * KDIM + k0);
    *reinterpret_cast<iv4*>(wf + b * 512 + l * 8) = pack8(src[0], src[1]);
}

__global__ __launch_bounds__(1024, 4) void linear_bf16_kernel(
    const float* __restrict__ x, const unsigned short* __restrict__ wf,
    const float* __restrict__ bias, float* __restrict__ out) {
    // B: 32 frag-blocks of 1KB per buffer (block = kk*16 + tile_local)
    __shared__ __attribute__((aligned(16))) unsigned short lds_b[3][32 * 512];  // 96 KB
    // A: 128 rows x 64 shorts, byte-XOR swizzle ^((row&7)<<4)
    __shared__ __attribute__((aligned(16))) unsigned short lds_a[2][BM * 64];   // 32 KB

    const int tid  = threadIdx.x;
    const int lane = tid & 63;
    const int wid  = tid >> 6;   // 0..15
    const int wr   = wid >> 3;   // 0..1  -> 64-row block
    const int wc   = wid & 7;    // 0..7  -> 32-col strip (per pass)
    const int fr   = lane & 15;
    const int fc   = lane >> 4;  // 0..3

    const int rowbase = blockIdx.x * BM;

    // ---- A staging coords: thread -> row tid>>3 (0..127), quarter tid&7 ----
    const int arow = tid >> 3;
    const int q    = tid & 7;
    const float* xbase = x + (size_t)(rowbase + arow) * KDIM + q * 4;
    const int aw0 = arow * 64 + ((q * 4)      ^ ((arow & 7) << 3));
    const int aw1 = arow * 64 + ((32 + q * 4) ^ ((arow & 7) << 3));

    fv4 ra[2][2];
    auto LOADA = [&](int slot, int S) {
        const int k64 = S & 7;
        ra[slot][0] = *reinterpret_cast<const fv4*>(xbase + k64 * 64);
        ra[slot][1] = *reinterpret_cast<const fv4*>(xbase + k64 * 64 + 32);
    };
    auto PACKA = [&](int ab, int slot) {
        union { unsigned short us[4]; iv2 v; } p0, p1;
#pragma unroll
        for (int i = 0; i < 4; ++i) {
            p0.us[i] = f2bf(ra[slot][0][i]);
            p1.us[i] = f2bf(ra[slot][1][i]);
        }
        *reinterpret_cast<iv2*>(&lds_a[ab][aw0]) = p0.v;
        *reinterpret_cast<iv2*>(&lds_a[ab][aw1]) = p1.v;
    };
    // stage B half-tile for step S: 32 KB = 16 waves x 2 DMA issues of 1KB
    auto STAGEB = [&](int bb, int S) {
        const int p = S >> 3, k64 = S & 7;
#pragma unroll
        for (int i = 0; i < 2; ++i) {
            const unsigned short* g =
                wf + (size_t)(((2 * k64 + i) * 32 + p * 16 + wid) * 512) + lane * 8;
            glds16(g, &lds_b[bb][(i * 16 + wid) * 512]);
        }
    };

    f32x4 acc[4][2];
#pragma unroll
    for (int m = 0; m < 4; ++m)
#pragma unroll
        for (int n = 0; n < 2; ++n)
            acc[m][n] = (f32x4){0.f, 0.f, 0.f, 0.f};

    auto COMPUTE = [&](int bb, int ab) {
#pragma unroll
        for (int kk = 0; kk < 2; ++kk) {
            bf16x8 bfr[2], af[4];
#pragma unroll
            for (int n = 0; n < 2; ++n)
                bfr[n] = *reinterpret_cast<const bf16x8*>(
                    &lds_b[bb][(kk * 16 + wc * 2 + n) * 512 + lane * 8]);
#pragma unroll
            for (int m = 0; m < 4; ++m)
                af[m] = *reinterpret_cast<const bf16x8*>(
                    &lds_a[ab][(wr * 64 + m * 16 + fr) * 64 +
                               ((kk * 32 + fc * 8) ^ ((fr & 7) << 3))]);
#pragma unroll
            for (int n = 0; n < 2; ++n)
#pragma unroll
                for (int m = 0; m < 4; ++m)
                    acc[m][n] = __builtin_amdgcn_mfma_f32_16x16x32_bf16(
                        af[m], bfr[n], acc[m][n], 0, 0, 0);
        }
    };

    auto STORE = [&](int p) {
        float bv[2];
#pragma unroll
        for (int n = 0; n < 2; ++n)
            bv[n] = bias[p * 256 + wc * 32 + n * 16 + fr];
        float* ob = out + (size_t)(rowbase + wr * 64 + fc * 4) * NDIM +
                    p * 256 + wc * 32 + fr;
#pragma unroll
        for (int m = 0; m < 4; ++m)
#pragma unroll
            for (int j = 0; j < 4; ++j) {
                float* orow = ob + (m * 16 + j) * NDIM;
#pragma unroll
                for (int n = 0; n < 2; ++n)
                    orow[n * 16] = acc[m][n][j] + bv[n];
            }
    };

    // ---- prologue: stage steps 0,1 (B DMA + A regs); A(0) into LDS ----
    STAGEB(0, 0);
    LOADA(0, 0);
    STAGEB(1, 1);
    LOADA(1, 1);
    PACKA(0, 0);  // implicit counted vmcnt drains B(0)+A(0); B(1)+A(1) fly on
    asm volatile("s_waitcnt vmcnt(4) lgkmcnt(0)" ::: "memory");
    __builtin_amdgcn_s_barrier();
    __builtin_amdgcn_sched_barrier(0);

#pragma unroll
    for (int S = 0; S < NSTEP; ++S) {
        if (S == 8) {  // pass-0 stores overlap step-8 compute; drained at s8 barrier
            STORE(0);
#pragma unroll
            for (int m = 0; m < 4; ++m)
#pragma unroll
                for (int n = 0; n < 2; ++n)
                    acc[m][n] = (f32x4){0.f, 0.f, 0.f, 0.f};
        }
        if (S + 2 < NSTEP) {
            STAGEB((S + 2) % 3, S + 2);  // B DMA, 2 steps ahead
            LOADA(S & 1, S + 2);         // A regs, 2 steps ahead
        }
        COMPUTE(S % 3, S & 1);
        if (S + 1 < NSTEP) PACKA((S + 1) & 1, (S + 1) & 1);
        if (S + 1 < NSTEP) {
            // counted: keep next stage-group (4 vmem) in flight across barrier
            asm volatile("s_waitcnt vmcnt(4) lgkmcnt(0)" ::: "memory");
            __builtin_amdgcn_s_barrier();
            __builtin_amdgcn_sched_barrier(0);
        }
    }
    STORE(1);
}

extern "C" void kernel_launch(void* const* d_in, const int* in_sizes, int n_in,
                              void* d_out, int out_size, void* d_ws, size_t ws_size,
                              hipStream_t stream) {
    const float* x    = (const float*)d_in[0];
    const float* w    = (const float*)d_in[1];
    const float* bias = (const float*)d_in[2];
    float* out        = (float*)d_out;
    unsigned short* wf = (unsigned short*)d_ws;  // 512 KB

    hipLaunchKernelGGL(repack_w_kernel, dim3(128), dim3(256), 0, stream, w, wf);
    hipLaunchKernelGGL(linear_bf16_kernel, dim3(M_TOTAL / BM), dim3(1024), 0, stream,
                       x, wf, bias, out);
}